// Round 16
// baseline (185.545 us; speedup 1.0000x reference)
//
#include <hip/hip_runtime.h>

// 2-layer fused LSTM + linear head.  B=8192, T=128, D=32, H=64, gates=256.
// R16 = R15 (1024 thr / 16 waves, BT=32, grid 256, single barrier domain,
// MFMA cluster + setprio, x prefetch, packed-f32 elem pairs) + PADE TANH:
// tanh(c) via Pade(7,6) rational with fmed3 clamp to +-6 (err <= ~5e-4)
// replaces the Ec=exp2(-2L2E*c) path: -2 trans ops per pair (12 -> 10),
// +6 packed VALU ops -> net ~-160cy/SIMD/step on the dominant pipe.
// Denominator rcp still merged with the output-gate sigmoid (one rcp both).
// Wave wv -> batch-half bh=wv>>3, h-block hw=wv&7 (h in [8hw,8hw+8)).
// log2e folded into weights (i,f,o x1.4427; g x2.8854); merged-rcp gate math.

#define TT  128
#define DIN 32
#define BT  32
#define L2E 1.44269504088896340736f

typedef _Float16 h8 __attribute__((ext_vector_type(8)));
typedef __fp16   p2 __attribute__((ext_vector_type(2)));
typedef float    f4 __attribute__((ext_vector_type(4)));
typedef float    f2 __attribute__((ext_vector_type(2)));

#define MFMA(A, B, C) __builtin_amdgcn_mfma_f32_16x16x32_f16((A), (B), (C), 0, 0, 0)

__device__ __forceinline__ h8 cvt8s(const float* p, float s) {
    float4 a = *(const float4*)p;
    float4 b = *(const float4*)(p + 4);
    union { h8 v; p2 q[4]; } u;
    u.q[0] = __builtin_amdgcn_cvt_pkrtz(a.x * s, a.y * s);
    u.q[1] = __builtin_amdgcn_cvt_pkrtz(a.z * s, a.w * s);
    u.q[2] = __builtin_amdgcn_cvt_pkrtz(b.x * s, b.y * s);
    u.q[3] = __builtin_amdgcn_cvt_pkrtz(b.z * s, b.w * s);
    return u.v;
}

__device__ __forceinline__ h8 pack8(const float4& a, const float4& b) {
    union { h8 v; p2 q[4]; } u;
    u.q[0] = __builtin_amdgcn_cvt_pkrtz(a.x, a.y);
    u.q[1] = __builtin_amdgcn_cvt_pkrtz(a.z, a.w);
    u.q[2] = __builtin_amdgcn_cvt_pkrtz(b.x, b.y);
    u.q[3] = __builtin_amdgcn_cvt_pkrtz(b.z, b.w);
    return u.v;
}

// Pairwise elem: A,B = gate accs {yi',yf',yg'(2x),yo'} of two h-elements
// (log2e pre-folded).  c = their cell states (f2).  Returns {hA, hB}.
// 10 trans (8 exp2 + 2 rcp) per pair; tanh(c) is a Pade(7,6) rational.
__device__ __forceinline__ f2 elem2(const f4& A, const f4& B, f2& c) {
    f2 Ei = { __builtin_amdgcn_exp2f(-A[0]), __builtin_amdgcn_exp2f(-B[0]) };
    f2 Ef = { __builtin_amdgcn_exp2f(-A[1]), __builtin_amdgcn_exp2f(-B[1]) };
    f2 Eg = { __builtin_amdgcn_exp2f(-A[2]), __builtin_amdgcn_exp2f(-B[2]) };
    f2 Eo = { __builtin_amdgcn_exp2f(-A[3]), __builtin_amdgcn_exp2f(-B[3]) };
    const f2 one = {1.f, 1.f};
    f2 a = one + Ei, b = one + Eg, d = one + Ef;
    f2 P = a * b;
    f2 N = c * P + (one - Eg) * d;
    f2 Pd = P * d;
    f2 rPd = { __builtin_amdgcn_rcpf(Pd[0]), __builtin_amdgcn_rcpf(Pd[1]) };
    c = N * rPd;
    // tanh(c) ~= t*(s^3+378s^2+17325s+135135)/(28s^3+3150s^2+62370s+135135),
    // t = clamp(c, -6, 6), s = t*t.  err <= ~5e-4 incl. clamp tail.
    f2 t = { __builtin_amdgcn_fmed3f(c[0], -6.f, 6.f),
             __builtin_amdgcn_fmed3f(c[1], -6.f, 6.f) };
    f2 s = t * t;
    f2 num = s + (f2){378.f, 378.f};
    num = num * s + (f2){17325.f, 17325.f};
    num = num * s + (f2){135135.f, 135135.f};
    num = num * t;
    f2 den = (f2){28.f, 28.f} * s + (f2){3150.f, 3150.f};
    den = den * s + (f2){62370.f, 62370.f};
    den = den * s + (f2){135135.f, 135135.f};
    f2 q = den * (one + Eo);
    f2 rq = { __builtin_amdgcn_rcpf(q[0]), __builtin_amdgcn_rcpf(q[1]) };
    return num * rq;
}

__global__ __launch_bounds__(1024, 4)
void lstm2_fused(const float* __restrict__ x,
                 const float* __restrict__ wih0, const float* __restrict__ whh0,
                 const float* __restrict__ bih0, const float* __restrict__ bhh0,
                 const float* __restrict__ wih1, const float* __restrict__ whh1,
                 const float* __restrict__ bih1, const float* __restrict__ bhh1,
                 const float* __restrict__ fcw,  const float* __restrict__ fcb,
                 float* __restrict__ out)
{
    const int tid  = threadIdx.x;
    const int lane = tid & 63;
    const int wv   = tid >> 6;      // 0..15
    const int hw   = wv & 7;        // h block 8*hw
    const int bh   = wv >> 3;       // batch half 0/1
    const int bl   = lane & 15;
    const int kg   = lane >> 4;

    // [layer][parity][b (32 rows)][h (64)] f16, XOR-swizzled; 16 KB
    __shared__ alignas(16) unsigned short hb[2][2][BT * 64];
    __shared__ float wpart[16][16];

    for (int i = tid; i < (int)(sizeof(hb) / 4); i += 1024) ((int*)hb)[i] = 0;

    // ---- weights: gate-interleaved row tiles, log2e folded ----
    h8 W0[2][3], W1[2][4];
    f4 b0v[2], b1v[2];
    #pragma unroll
    for (int t = 0; t < 2; ++t) {
        const int hbse = 8 * hw + 4 * t;
        const int gam  = bl & 3;                         // gate of this A-row
        const int g    = 64 * gam + hbse + (bl >> 2);    // global weight row
        const float sc = (gam == 2) ? 2.f * L2E : L2E;
        W0[t][0] = cvt8s(wih0 + g * 32 + 8 * kg, sc);
        W0[t][1] = cvt8s(whh0 + g * 64 + 8 * kg, sc);
        W0[t][2] = cvt8s(whh0 + g * 64 + 32 + 8 * kg, sc);
        W1[t][0] = cvt8s(wih1 + g * 64 + 8 * kg, sc);
        W1[t][1] = cvt8s(wih1 + g * 64 + 32 + 8 * kg, sc);
        W1[t][2] = cvt8s(whh1 + g * 64 + 8 * kg, sc);
        W1[t][3] = cvt8s(whh1 + g * 64 + 32 + 8 * kg, sc);
        #pragma unroll
        for (int r = 0; r < 4; ++r) {
            const int gr = 64 * r + hbse + kg;           // D element r = gate r of h=hbse+kg
            const float scr = (r == 2) ? 2.f * L2E : L2E;
            b0v[t][r] = (bih0[gr] + bhh0[gr]) * scr;
            b1v[t][r] = (bih1[gr] + bhh1[gr]) * scr;
        }
    }

    const int bbase = blockIdx.x * BT;
    const int brow  = 16 * bh + bl;                      // batch row within block
    const float* xp = x + (size_t)(bbase + brow) * (TT * DIN) + 8 * kg;

    f2 c0 = {0.f, 0.f}, c1 = {0.f, 0.f}, h1f = {0.f, 0.f};

    __syncthreads();   // LDS zero visible

    const int swz = (brow & 7) << 4;
    char* lb = (char*)hb;
    const int rowoff = brow * 128;
    const int rd0 = rowoff + ((16 * kg) ^ swz);
    const int rd1 = rowoff + ((64 + 16 * kg) ^ swz);
    const int wro0 = rowoff + ((16 * hw + 2 * kg) ^ swz);        // h = 8hw+kg   (t=0)
    const int wro1 = rowoff + ((16 * hw + 8 + 2 * kg) ^ swz);    // h = 8hw+4+kg (t=1)

    h8 xcur;

    // One skewed step: {L0[it], L1[it-1]}; MFMA cluster first, then elems.
    // Parity regions: 4096 B (2 parity x 32 rows x 128 B per layer).
    auto STEP = [&](int wp, int rp, const float* xnext) {
        float4 xnA, xnB;
        if (xnext) { xnA = *(const float4*)xnext; xnB = *(const float4*)(xnext + 4); }

        h8 hr0 = *(const h8*)(lb + rp * 4096 + rd0);          // h0[it-1]
        h8 hr1 = *(const h8*)(lb + rp * 4096 + rd1);
        h8 g1a = *(const h8*)(lb + 8192 + rp * 4096 + rd0);   // h1[it-2]
        h8 g1b = *(const h8*)(lb + 8192 + rp * 4096 + rd1);

        __builtin_amdgcn_s_setprio(1);
        f4 a00 = b0v[0];
        a00 = MFMA(W0[0][1], hr0, a00);
        a00 = MFMA(W0[0][2], hr1, a00);
        a00 = MFMA(W0[0][0], xcur, a00);
        f4 a01 = b0v[1];
        a01 = MFMA(W0[1][1], hr0, a01);
        a01 = MFMA(W0[1][2], hr1, a01);
        a01 = MFMA(W0[1][0], xcur, a01);
        f4 a10 = b1v[0];
        a10 = MFMA(W1[0][0], hr0, a10);
        a10 = MFMA(W1[0][1], hr1, a10);
        a10 = MFMA(W1[0][2], g1a, a10);
        a10 = MFMA(W1[0][3], g1b, a10);
        f4 a11 = b1v[1];
        a11 = MFMA(W1[1][0], hr0, a11);
        a11 = MFMA(W1[1][1], hr1, a11);
        a11 = MFMA(W1[1][2], g1a, a11);
        a11 = MFMA(W1[1][3], g1b, a11);
        __builtin_amdgcn_s_setprio(0);

        f2 h0p = elem2(a00, a01, c0);
        f2 h1p = elem2(a10, a11, c1);
        h1f = h1p;

        *(_Float16*)(lb + wp * 4096 + wro0) = (_Float16)h0p[0];
        *(_Float16*)(lb + wp * 4096 + wro1) = (_Float16)h0p[1];
        *(_Float16*)(lb + 8192 + wp * 4096 + wro0) = (_Float16)h1p[0];
        *(_Float16*)(lb + 8192 + wp * 4096 + wro1) = (_Float16)h1p[1];

        if (xnext) xcur = pack8(xnA, xnB);
        __syncthreads();
    };

    // ---- it = 0: L0 only (t=0); h0[-1]=0 from zeroed parity-1 buffer ----
    {
        float4 x0a = *(const float4*)(xp);
        float4 x0b = *(const float4*)(xp + 4);
        float4 xnA = *(const float4*)(xp + DIN);       // prefetch x[1]
        float4 xnB = *(const float4*)(xp + DIN + 4);
        h8 xc  = pack8(x0a, x0b);
        h8 hr0 = *(const h8*)(lb + 4096 + rd0);
        h8 hr1 = *(const h8*)(lb + 4096 + rd1);
        __builtin_amdgcn_s_setprio(1);
        f4 a00 = b0v[0];
        a00 = MFMA(W0[0][1], hr0, a00);
        a00 = MFMA(W0[0][2], hr1, a00);
        a00 = MFMA(W0[0][0], xc, a00);
        f4 a01 = b0v[1];
        a01 = MFMA(W0[1][1], hr0, a01);
        a01 = MFMA(W0[1][2], hr1, a01);
        a01 = MFMA(W0[1][0], xc, a01);
        __builtin_amdgcn_s_setprio(0);
        f2 h0p = elem2(a00, a01, c0);
        *(_Float16*)(lb + 0 * 4096 + wro0) = (_Float16)h0p[0];
        *(_Float16*)(lb + 0 * 4096 + wro1) = (_Float16)h0p[1];
        xcur = pack8(xnA, xnB);
        __syncthreads();
    }

    // ---- it = 1..126 unrolled x2 (parities literal), then peel it=127 ----
    for (int itp = 1; itp < TT - 1; itp += 2) {
        STEP(1, 0, xp + (itp + 1) * DIN);   // it = itp   (odd)
        STEP(0, 1, xp + (itp + 2) * DIN);   // it = itp+1 (even)
    }
    STEP(1, 0, nullptr);                    // it = 127

    // ---- tail: L1 for t = TT-1 (reads parity 1) ----
    {
        h8 hr0 = *(const h8*)(lb + 4096 + rd0);              // h0[127]
        h8 hr1 = *(const h8*)(lb + 4096 + rd1);
        h8 g1a = *(const h8*)(lb + 8192 + 4096 + rd0);       // h1[126]
        h8 g1b = *(const h8*)(lb + 8192 + 4096 + rd1);
        f4 a10 = b1v[0];
        a10 = MFMA(W1[0][0], hr0, a10);
        a10 = MFMA(W1[0][1], hr1, a10);
        a10 = MFMA(W1[0][2], g1a, a10);
        a10 = MFMA(W1[0][3], g1b, a10);
        f4 a11 = b1v[1];
        a11 = MFMA(W1[1][0], hr0, a11);
        a11 = MFMA(W1[1][1], hr1, a11);
        a11 = MFMA(W1[1][2], g1a, a11);
        a11 = MFMA(W1[1][3], g1b, a11);
        h1f = elem2(a10, a11, c1);
    }

    // ---- head: out[b] = h1 . fc_w + fc_b ----
    float part = h1f[0] * fcw[8 * hw + kg] + h1f[1] * fcw[8 * hw + 4 + kg];
    part += __shfl_xor(part, 16, 64);
    part += __shfl_xor(part, 32, 64);
    if (lane < 16) wpart[wv][lane] = part;
    __syncthreads();
    if (tid < BT) {
        const int tbh = tid >> 4, tbl = tid & 15;
        float s = fcb[0];
        #pragma unroll
        for (int w = 0; w < 8; ++w) s += wpart[8 * tbh + w][tbl];
        out[bbase + tid] = s;
    }
}

extern "C" void kernel_launch(void* const* d_in, const int* in_sizes, int n_in,
                              void* d_out, int out_size, void* d_ws, size_t ws_size,
                              hipStream_t stream) {
    (void)in_sizes; (void)n_in; (void)d_ws; (void)ws_size; (void)out_size;
    lstm2_fused<<<dim3(8192 / BT), dim3(1024), 0, stream>>>(
        (const float*)d_in[0],
        (const float*)d_in[1], (const float*)d_in[2],
        (const float*)d_in[3], (const float*)d_in[4],
        (const float*)d_in[5], (const float*)d_in[6],
        (const float*)d_in[7], (const float*)d_in[8],
        (const float*)d_in[9], (const float*)d_in[10],
        (float*)d_out);
}

// Round 17
// 175.706 us; speedup vs baseline: 1.0560x; 1.0560x over previous
//
#include <hip/hip_runtime.h>

// 2-layer fused LSTM + linear head.  B=8192, T=128, D=32, H=64, gates=256.
// R17 = R15 exact revert (best kernel, 175.8 us): 1024 thr / 16 waves,
// BT=32, grid 256 -> 1 block/CU, single barrier domain, MFMA cluster +
// setprio, x prefetch, PACKED-F32 elem pairs (v_pk_* for all non-trans
// algebra), hw trans (5 exp2 + 2 rcp per element — R8/R16 both proved
// polynomial/rational replacements regress).
// Wave wv -> batch-half bh=wv>>3, h-block hw=wv&7 (h in [8hw,8hw+8)).
// log2e folded into weights (i,f,o x1.4427; g x2.8854); merged-rcp gate math.

#define TT  128
#define DIN 32
#define BT  32
#define L2E 1.44269504088896340736f

typedef _Float16 h8 __attribute__((ext_vector_type(8)));
typedef __fp16   p2 __attribute__((ext_vector_type(2)));
typedef float    f4 __attribute__((ext_vector_type(4)));
typedef float    f2 __attribute__((ext_vector_type(2)));

#define MFMA(A, B, C) __builtin_amdgcn_mfma_f32_16x16x32_f16((A), (B), (C), 0, 0, 0)

__device__ __forceinline__ h8 cvt8s(const float* p, float s) {
    float4 a = *(const float4*)p;
    float4 b = *(const float4*)(p + 4);
    union { h8 v; p2 q[4]; } u;
    u.q[0] = __builtin_amdgcn_cvt_pkrtz(a.x * s, a.y * s);
    u.q[1] = __builtin_amdgcn_cvt_pkrtz(a.z * s, a.w * s);
    u.q[2] = __builtin_amdgcn_cvt_pkrtz(b.x * s, b.y * s);
    u.q[3] = __builtin_amdgcn_cvt_pkrtz(b.z * s, b.w * s);
    return u.v;
}

__device__ __forceinline__ h8 pack8(const float4& a, const float4& b) {
    union { h8 v; p2 q[4]; } u;
    u.q[0] = __builtin_amdgcn_cvt_pkrtz(a.x, a.y);
    u.q[1] = __builtin_amdgcn_cvt_pkrtz(a.z, a.w);
    u.q[2] = __builtin_amdgcn_cvt_pkrtz(b.x, b.y);
    u.q[3] = __builtin_amdgcn_cvt_pkrtz(b.z, b.w);
    return u.v;
}

// Pairwise elem: A,B = gate accs {yi',yf',yg'(2x),yo'} of two h-elements
// (log2e pre-folded).  c = their cell states (f2).  Returns {hA, hB}.
// Trans ops stay scalar (8 exp2 + 4 rcp); all algebra is float2 -> VOP3P.
__device__ __forceinline__ f2 elem2(const f4& A, const f4& B, f2& c) {
    f2 Ei = { __builtin_amdgcn_exp2f(-A[0]), __builtin_amdgcn_exp2f(-B[0]) };
    f2 Ef = { __builtin_amdgcn_exp2f(-A[1]), __builtin_amdgcn_exp2f(-B[1]) };
    f2 Eg = { __builtin_amdgcn_exp2f(-A[2]), __builtin_amdgcn_exp2f(-B[2]) };
    f2 Eo = { __builtin_amdgcn_exp2f(-A[3]), __builtin_amdgcn_exp2f(-B[3]) };
    const f2 one = {1.f, 1.f};
    f2 a = one + Ei, b = one + Eg, d = one + Ef;
    f2 P = a * b;
    f2 N = c * P + (one - Eg) * d;
    f2 Pd = P * d;
    f2 rPd = { __builtin_amdgcn_rcpf(Pd[0]), __builtin_amdgcn_rcpf(Pd[1]) };
    c = N * rPd;
    f2 Ec = { __builtin_amdgcn_exp2f(-2.f * L2E * c[0]),
              __builtin_amdgcn_exp2f(-2.f * L2E * c[1]) };
    f2 q = (one + Ec) * (one + Eo);
    f2 rq = { __builtin_amdgcn_rcpf(q[0]), __builtin_amdgcn_rcpf(q[1]) };
    return (one - Ec) * rq;
}

__global__ __launch_bounds__(1024, 4)
void lstm2_fused(const float* __restrict__ x,
                 const float* __restrict__ wih0, const float* __restrict__ whh0,
                 const float* __restrict__ bih0, const float* __restrict__ bhh0,
                 const float* __restrict__ wih1, const float* __restrict__ whh1,
                 const float* __restrict__ bih1, const float* __restrict__ bhh1,
                 const float* __restrict__ fcw,  const float* __restrict__ fcb,
                 float* __restrict__ out)
{
    const int tid  = threadIdx.x;
    const int lane = tid & 63;
    const int wv   = tid >> 6;      // 0..15
    const int hw   = wv & 7;        // h block 8*hw
    const int bh   = wv >> 3;       // batch half 0/1
    const int bl   = lane & 15;
    const int kg   = lane >> 4;

    // [layer][parity][b (32 rows)][h (64)] f16, XOR-swizzled; 16 KB
    __shared__ alignas(16) unsigned short hb[2][2][BT * 64];
    __shared__ float wpart[16][16];

    for (int i = tid; i < (int)(sizeof(hb) / 4); i += 1024) ((int*)hb)[i] = 0;

    // ---- weights: gate-interleaved row tiles, log2e folded ----
    h8 W0[2][3], W1[2][4];
    f4 b0v[2], b1v[2];
    #pragma unroll
    for (int t = 0; t < 2; ++t) {
        const int hbse = 8 * hw + 4 * t;
        const int gam  = bl & 3;                         // gate of this A-row
        const int g    = 64 * gam + hbse + (bl >> 2);    // global weight row
        const float sc = (gam == 2) ? 2.f * L2E : L2E;
        W0[t][0] = cvt8s(wih0 + g * 32 + 8 * kg, sc);
        W0[t][1] = cvt8s(whh0 + g * 64 + 8 * kg, sc);
        W0[t][2] = cvt8s(whh0 + g * 64 + 32 + 8 * kg, sc);
        W1[t][0] = cvt8s(wih1 + g * 64 + 8 * kg, sc);
        W1[t][1] = cvt8s(wih1 + g * 64 + 32 + 8 * kg, sc);
        W1[t][2] = cvt8s(whh1 + g * 64 + 8 * kg, sc);
        W1[t][3] = cvt8s(whh1 + g * 64 + 32 + 8 * kg, sc);
        #pragma unroll
        for (int r = 0; r < 4; ++r) {
            const int gr = 64 * r + hbse + kg;           // D element r = gate r of h=hbse+kg
            const float scr = (r == 2) ? 2.f * L2E : L2E;
            b0v[t][r] = (bih0[gr] + bhh0[gr]) * scr;
            b1v[t][r] = (bih1[gr] + bhh1[gr]) * scr;
        }
    }

    const int bbase = blockIdx.x * BT;
    const int brow  = 16 * bh + bl;                      // batch row within block
    const float* xp = x + (size_t)(bbase + brow) * (TT * DIN) + 8 * kg;

    f2 c0 = {0.f, 0.f}, c1 = {0.f, 0.f}, h1f = {0.f, 0.f};

    __syncthreads();   // LDS zero visible

    const int swz = (brow & 7) << 4;
    char* lb = (char*)hb;
    const int rowoff = brow * 128;
    const int rd0 = rowoff + ((16 * kg) ^ swz);
    const int rd1 = rowoff + ((64 + 16 * kg) ^ swz);
    const int wro0 = rowoff + ((16 * hw + 2 * kg) ^ swz);        // h = 8hw+kg   (t=0)
    const int wro1 = rowoff + ((16 * hw + 8 + 2 * kg) ^ swz);    // h = 8hw+4+kg (t=1)

    h8 xcur;

    // One skewed step: {L0[it], L1[it-1]}; MFMA cluster first, then elems.
    // Parity regions: 4096 B (2 parity x 32 rows x 128 B per layer).
    auto STEP = [&](int wp, int rp, const float* xnext) {
        float4 xnA, xnB;
        if (xnext) { xnA = *(const float4*)xnext; xnB = *(const float4*)(xnext + 4); }

        h8 hr0 = *(const h8*)(lb + rp * 4096 + rd0);          // h0[it-1]
        h8 hr1 = *(const h8*)(lb + rp * 4096 + rd1);
        h8 g1a = *(const h8*)(lb + 8192 + rp * 4096 + rd0);   // h1[it-2]
        h8 g1b = *(const h8*)(lb + 8192 + rp * 4096 + rd1);

        __builtin_amdgcn_s_setprio(1);
        f4 a00 = b0v[0];
        a00 = MFMA(W0[0][1], hr0, a00);
        a00 = MFMA(W0[0][2], hr1, a00);
        a00 = MFMA(W0[0][0], xcur, a00);
        f4 a01 = b0v[1];
        a01 = MFMA(W0[1][1], hr0, a01);
        a01 = MFMA(W0[1][2], hr1, a01);
        a01 = MFMA(W0[1][0], xcur, a01);
        f4 a10 = b1v[0];
        a10 = MFMA(W1[0][0], hr0, a10);
        a10 = MFMA(W1[0][1], hr1, a10);
        a10 = MFMA(W1[0][2], g1a, a10);
        a10 = MFMA(W1[0][3], g1b, a10);
        f4 a11 = b1v[1];
        a11 = MFMA(W1[1][0], hr0, a11);
        a11 = MFMA(W1[1][1], hr1, a11);
        a11 = MFMA(W1[1][2], g1a, a11);
        a11 = MFMA(W1[1][3], g1b, a11);
        __builtin_amdgcn_s_setprio(0);

        f2 h0p = elem2(a00, a01, c0);
        f2 h1p = elem2(a10, a11, c1);
        h1f = h1p;

        *(_Float16*)(lb + wp * 4096 + wro0) = (_Float16)h0p[0];
        *(_Float16*)(lb + wp * 4096 + wro1) = (_Float16)h0p[1];
        *(_Float16*)(lb + 8192 + wp * 4096 + wro0) = (_Float16)h1p[0];
        *(_Float16*)(lb + 8192 + wp * 4096 + wro1) = (_Float16)h1p[1];

        if (xnext) xcur = pack8(xnA, xnB);
        __syncthreads();
    };

    // ---- it = 0: L0 only (t=0); h0[-1]=0 from zeroed parity-1 buffer ----
    {
        float4 x0a = *(const float4*)(xp);
        float4 x0b = *(const float4*)(xp + 4);
        float4 xnA = *(const float4*)(xp + DIN);       // prefetch x[1]
        float4 xnB = *(const float4*)(xp + DIN + 4);
        h8 xc  = pack8(x0a, x0b);
        h8 hr0 = *(const h8*)(lb + 4096 + rd0);
        h8 hr1 = *(const h8*)(lb + 4096 + rd1);
        __builtin_amdgcn_s_setprio(1);
        f4 a00 = b0v[0];
        a00 = MFMA(W0[0][1], hr0, a00);
        a00 = MFMA(W0[0][2], hr1, a00);
        a00 = MFMA(W0[0][0], xc, a00);
        f4 a01 = b0v[1];
        a01 = MFMA(W0[1][1], hr0, a01);
        a01 = MFMA(W0[1][2], hr1, a01);
        a01 = MFMA(W0[1][0], xc, a01);
        __builtin_amdgcn_s_setprio(0);
        f2 h0p = elem2(a00, a01, c0);
        *(_Float16*)(lb + 0 * 4096 + wro0) = (_Float16)h0p[0];
        *(_Float16*)(lb + 0 * 4096 + wro1) = (_Float16)h0p[1];
        xcur = pack8(xnA, xnB);
        __syncthreads();
    }

    // ---- it = 1..126 unrolled x2 (parities literal), then peel it=127 ----
    for (int itp = 1; itp < TT - 1; itp += 2) {
        STEP(1, 0, xp + (itp + 1) * DIN);   // it = itp   (odd)
        STEP(0, 1, xp + (itp + 2) * DIN);   // it = itp+1 (even)
    }
    STEP(1, 0, nullptr);                    // it = 127

    // ---- tail: L1 for t = TT-1 (reads parity 1) ----
    {
        h8 hr0 = *(const h8*)(lb + 4096 + rd0);              // h0[127]
        h8 hr1 = *(const h8*)(lb + 4096 + rd1);
        h8 g1a = *(const h8*)(lb + 8192 + 4096 + rd0);       // h1[126]
        h8 g1b = *(const h8*)(lb + 8192 + 4096 + rd1);
        f4 a10 = b1v[0];
        a10 = MFMA(W1[0][0], hr0, a10);
        a10 = MFMA(W1[0][1], hr1, a10);
        a10 = MFMA(W1[0][2], g1a, a10);
        a10 = MFMA(W1[0][3], g1b, a10);
        f4 a11 = b1v[1];
        a11 = MFMA(W1[1][0], hr0, a11);
        a11 = MFMA(W1[1][1], hr1, a11);
        a11 = MFMA(W1[1][2], g1a, a11);
        a11 = MFMA(W1[1][3], g1b, a11);
        h1f = elem2(a10, a11, c1);
    }

    // ---- head: out[b] = h1 . fc_w + fc_b ----
    float part = h1f[0] * fcw[8 * hw + kg] + h1f[1] * fcw[8 * hw + 4 + kg];
    part += __shfl_xor(part, 16, 64);
    part += __shfl_xor(part, 32, 64);
    if (lane < 16) wpart[wv][lane] = part;
    __syncthreads();
    if (tid < BT) {
        const int tbh = tid >> 4, tbl = tid & 15;
        float s = fcb[0];
        #pragma unroll
        for (int w = 0; w < 8; ++w) s += wpart[8 * tbh + w][tbl];
        out[bbase + tid] = s;
    }
}

extern "C" void kernel_launch(void* const* d_in, const int* in_sizes, int n_in,
                              void* d_out, int out_size, void* d_ws, size_t ws_size,
                              hipStream_t stream) {
    (void)in_sizes; (void)n_in; (void)d_ws; (void)ws_size; (void)out_size;
    lstm2_fused<<<dim3(8192 / BT), dim3(1024), 0, stream>>>(
        (const float*)d_in[0],
        (const float*)d_in[1], (const float*)d_in[2],
        (const float*)d_in[3], (const float*)d_in[4],
        (const float*)d_in[5], (const float*)d_in[6],
        (const float*)d_in[7], (const float*)d_in[8],
        (const float*)d_in[9], (const float*)d_in[10],
        (float*)d_out);
}